// Round 3
// baseline (544.857 us; speedup 1.0000x reference)
//
#include <hip/hip_runtime.h>

typedef unsigned int u32;
typedef unsigned short u16;
typedef float f32x4 __attribute__((ext_vector_type(4)));
typedef __bf16 bf16x8 __attribute__((ext_vector_type(8)));

#define BATCH 128
#define NIN   1024
#define DIN   256
#define NC    16
#define DC    32
#define NCOL  512

__device__ __forceinline__ float bflo(u32 v){ return __uint_as_float(v << 16); }
__device__ __forceinline__ float bfhi(u32 v){ return __uint_as_float(v & 0xffff0000u); }
__device__ __forceinline__ u32 bfround(u32 ua){ return (ua + 0x7fffu + ((ua >> 16) & 1u)) >> 16; }
__device__ __forceinline__ u32 pack2(float a, float b){
    return (bfround(__float_as_uint(a)) & 0xffffu) | (bfround(__float_as_uint(b)) << 16);
}
__device__ __forceinline__ bf16x8 ldfrag(const u16* p){
    return __builtin_bit_cast(bf16x8, *(const uint4*)p);
}

// Swizzled address (bf16 units) into the 32x256 bf16 transpose tile (r<=31 subset
// of the round-0-verified 64-row swizzle; same conflict-free properties).
__device__ __forceinline__ int lds_x(int r, int d){
    int sw = (d >> 2) ^ ((r & 7) << 1) ^ (((r >> 3) & 3) << 2);
    return r * 256 + (sw << 2) + (d & 3);
}

// K0: per (b, 32-row j-chunk):
//   xb : row-major bf16 x [b][j][d]
//   xbT: j-contiguous MFMA B-fragment order uint4[((b*16+dt)*32+js)*64+lane]
//        lane(l15,q) = x[js*32+q*8 .. +7][dt*16+l15]
//   s  : += column sums (register partials, 4 atomics/thread)
//   Wb : bf16 W [d][c]   WT : bf16 W^T [c][d]   (blocks with jc==0)
__global__ __launch_bounds__(256) void k_pre(const float* __restrict__ x, const float* __restrict__ W,
                                             uint4* __restrict__ xbT, u16* __restrict__ xb,
                                             float* __restrict__ s, uint2* __restrict__ Wb,
                                             uint2* __restrict__ WT){
    __shared__ __align__(16) u16 xt[32 * 256];   // 16 KB
    const int t = threadIdx.x, jc = blockIdx.x, b = blockIdx.y;

    if (jc == 0){   // W conversions, 128 blocks cover all of W
        int id = b * 256 + t;                    // 0..32767
        float4 w4 = ((const float4*)W)[id];
        Wb[id] = make_uint2(pack2(w4.x, w4.y), pack2(w4.z, w4.w));
        int c = id >> 6, d4 = id & 63;           // WT[c][4*d4 .. +3]
        float e0 = W[(size_t)(d4 * 4 + 0) * NCOL + c];
        float e1 = W[(size_t)(d4 * 4 + 1) * NCOL + c];
        float e2 = W[(size_t)(d4 * 4 + 2) * NCOL + c];
        float e3 = W[(size_t)(d4 * 4 + 3) * NCOL + c];
        WT[c * 64 + d4] = make_uint2(pack2(e0, e1), pack2(e2, e3));
    }
    {   // stage 32x256 fp32 -> swizzled bf16 LDS + row-major bf16 xb + register col-sums
        const float4* xg = (const float4*)(x + ((size_t)b * NIN + jc * 32) * DIN);
        uint2* xbw = (uint2*)xb + ((size_t)(b * NIN + jc * 32)) * 64;
        int d4 = t & 63, rg = t >> 6;
        float cs0 = 0.f, cs1 = 0.f, cs2 = 0.f, cs3 = 0.f;
        #pragma unroll
        for (int m = 0; m < 8; m++){
            int r = rg + 4 * m;
            float4 v = xg[r * 64 + d4];
            uint2 p = make_uint2(pack2(v.x, v.y), pack2(v.z, v.w));
            *(uint2*)&xt[lds_x(r, d4 * 4)] = p;
            xbw[r * 64 + d4] = p;
            cs0 += bflo(p.x); cs1 += bfhi(p.x);
            cs2 += bflo(p.y); cs3 += bfhi(p.y);
        }
        atomicAdd(&s[b * DIN + d4 * 4 + 0], cs0);
        atomicAdd(&s[b * DIN + d4 * 4 + 1], cs1);
        atomicAdd(&s[b * DIN + d4 * 4 + 2], cs2);
        atomicAdd(&s[b * DIN + d4 * 4 + 3], cs3);
    }
    __syncthreads();
    // transpose gather -> xbT (4 uint4 per thread, coalesced stores)
    #pragma unroll
    for (int w = 0; w < 4; w++){
        int oid = t + 256 * w;                    // 0..1023
        int lane = oid & 63, dt = oid >> 6;       // dt 0..15
        int l15 = lane & 15, q = lane >> 4;
        int rb = q * 8, d = dt * 16 + l15;
        u32 r[4];
        #pragma unroll
        for (int p = 0; p < 4; p++){
            u32 lo = xt[lds_x(rb + 2 * p, d)];
            u32 hi = xt[lds_x(rb + 2 * p + 1, d)];
            r[p] = lo | (hi << 16);
        }
        xbT[(((size_t)b * 16 + dt) * 32 + jc) * 64 + lane] = make_uint4(r[0], r[1], r[2], r[3]);
    }
}

// K1: fully fused routing — one block per b, 1024 threads, 3 iterations in LDS.
//   iter0: o = squash((s/16)W); then 3x { v = o.W^T ; bb = v.x^T (MFMA) ;
//   softmax_i ; z = c.x (MFMA via xbT) ; y = z.W ; squash }.
__global__ __launch_bounds__(1024) void k_fused(const u16* __restrict__ xb, const uint4* __restrict__ xbT,
                                                const float* __restrict__ s, const u16* __restrict__ Wb,
                                                const u32* __restrict__ WT32, float* __restrict__ out){
    __shared__ float bbl[16 * 1028];              // 65,792 B  (row stride 1028 f32)
    __shared__ __align__(16) u16 cl[16 * 1032];   // 33,024 B  (row stride 1032 u16)
    __shared__ float zl[16 * 260];                // 16,640 B
    __shared__ __align__(16) float ol[512];       //  2,048 B
    __shared__ __align__(16) u32 vfb[8 * 256];    //  8,192 B  v in frag order [ks][lane*4+e]
    __shared__ float yp[1024];                    //  4,096 B   (total ~127 KB)
    const int b = blockIdx.x, t = threadIdx.x;
    const int lane = t & 63, wv = t >> 6;         // 16 waves
    const int l15 = lane & 15, q = lane >> 4;

    // ---- iter 0: z row = s/16 (same for all i) ----
    if (t < 256) zl[t] = s[b * 256 + t] * (1.f / 16.f);
    __syncthreads();
    {   // y0 partial over half the d-range
        int h = t >> 9, c = t & 511;
        const u16* wp = Wb + (size_t)(h * 128) * 512 + c;
        float acc = 0.f;
        #pragma unroll 8
        for (int d = 0; d < 128; d++) acc += zl[h * 128 + d] * bflo((u32)wp[d * 512]);
        yp[t] = acc;
    }
    __syncthreads();
    if (t < 512){   // squash -> ol
        float yv = yp[t] + yp[t + 512];
        float s2 = yv * yv;
        s2 += __shfl_xor(s2, 1); s2 += __shfl_xor(s2, 2); s2 += __shfl_xor(s2, 4);
        s2 += __shfl_xor(s2, 8); s2 += __shfl_xor(s2, 16);
        ol[t] = yv / sqrtf(s2 + 1e-7f);
    }

    for (int it = 1; it <= 3; ++it){
        __syncthreads();
        // ---- v-step: v[i,d] = sum_k o[i,k] WT[32i+k][d] -> vfb (frag order) ----
        #pragma unroll
        for (int e2 = 0; e2 < 2; e2++){
            int wo = t + 1024 * e2;               // 0..2047 word ids
            int i = wo >> 7, dh = wo & 127;
            float a0 = 0.f, a1 = 0.f;
            #pragma unroll
            for (int k = 0; k < 32; k++){
                u32 wv2 = WT32[(size_t)(i * 32 + k) * 128 + dh];
                float ok = ol[i * 32 + k];
                a0 += ok * bflo(wv2); a1 += ok * bfhi(wv2);
            }
            int ks = dh >> 4, qq = (dh >> 2) & 3, e = dh & 3;
            vfb[ks * 256 + (qq * 16 + i) * 4 + e] = pack2(a0, a1);
        }
        __syncthreads();
        // ---- phase A: bb[i,j] = v . x^T  (A=v frags from LDS, B=x rows from global) ----
        {
            uint4 vf[8];
            #pragma unroll
            for (int ks = 0; ks < 8; ks++) vf[ks] = *(const uint4*)&vfb[ks * 256 + lane * 4];
            #pragma unroll
            for (int u = 0; u < 4; u++){
                int jt = wv * 4 + u;
                const u16* xr = xb + ((size_t)(b * NIN + jt * 16 + l15)) * 256 + q * 8;
                f32x4 acc = {0.f, 0.f, 0.f, 0.f};
                #pragma unroll
                for (int ks = 0; ks < 8; ks++)
                    acc = __builtin_amdgcn_mfma_f32_16x16x32_bf16(
                        __builtin_bit_cast(bf16x8, vf[ks]), ldfrag(xr + ks * 32), acc, 0, 0, 0);
                #pragma unroll
                for (int r = 0; r < 4; r++) bbl[(q * 4 + r) * 1028 + jt * 16 + l15] = acc[r];
            }
        }
        __syncthreads();
        // ---- softmax over i per column j ----
        {
            float mx = -1e30f, e[16], sum = 0.f;
            #pragma unroll
            for (int i = 0; i < 16; i++) mx = fmaxf(mx, bbl[i * 1028 + t]);
            #pragma unroll
            for (int i = 0; i < 16; i++){ e[i] = __expf(bbl[i * 1028 + t] - mx); sum += e[i]; }
            float inv = 1.f / sum;
            #pragma unroll
            for (int i = 0; i < 16; i++) cl[i * 1032 + t] = (u16)bfround(__float_as_uint(e[i] * inv));
        }
        __syncthreads();
        // ---- phase C: z[i,d] = c . x  (A=c frags from LDS, B=x^T frags from xbT) ----
        {
            int dt = wv;                          // wave owns one 16-d tile
            f32x4 acc = {0.f, 0.f, 0.f, 0.f};
            const uint4* xT = xbT + (((size_t)b * 16 + dt) * 32) * 64 + lane;
            #pragma unroll 8
            for (int js = 0; js < 32; js++){
                bf16x8 cf = ldfrag(&cl[l15 * 1032 + js * 32 + q * 8]);
                acc = __builtin_amdgcn_mfma_f32_16x16x32_bf16(cf, __builtin_bit_cast(bf16x8, xT[js * 64]), acc, 0, 0, 0);
            }
            #pragma unroll
            for (int r = 0; r < 4; r++) zl[(q * 4 + r) * 260 + dt * 16 + l15] = acc[r];
        }
        __syncthreads();
        // ---- y-step: y[i,k] = sum_d z[i,d] W[d,32i+k] ----
        {
            int h = t >> 9, c = t & 511, i = c >> 5;
            const u16* wp = Wb + (size_t)(h * 128) * 512 + c;
            float acc = 0.f;
            #pragma unroll 8
            for (int d = 0; d < 128; d++) acc += zl[i * 260 + h * 128 + d] * bflo((u32)wp[d * 512]);
            yp[t] = acc;
        }
        __syncthreads();
        if (t < 512){   // squash -> ol (or out on final iter)
            float yv = yp[t] + yp[t + 512];
            float s2 = yv * yv;
            s2 += __shfl_xor(s2, 1); s2 += __shfl_xor(s2, 2); s2 += __shfl_xor(s2, 4);
            s2 += __shfl_xor(s2, 8); s2 += __shfl_xor(s2, 16);
            float r = yv / sqrtf(s2 + 1e-7f);
            if (it == 3) out[b * NCOL + t] = r;
            else         ol[t] = r;
        }
    }
}

extern "C" void kernel_launch(void* const* d_in, const int* in_sizes, int n_in,
                              void* d_out, int out_size, void* d_ws, size_t ws_size,
                              hipStream_t stream){
    const float* x = (const float*)d_in[0];    // fp32 [128][1024][256]
    const float* W = (const float*)d_in[1];    // fp32 [256][512]
    float* out = (float*)d_out;                // fp32 [128][16][32]
    char* ws = (char*)d_ws;
    float* s    = (float*)(ws);                //   131,072 B : column sums
    u16*   Wb   = (u16*)  (ws + 131072);       //   262,144 B : W bf16 [d][c]
    u32*   WT   = (u32*)  (ws + 393216);       //   262,144 B : W^T bf16 [c][d]
    u16*   xb   = (u16*)  (ws + 655360);       // 67,108,864 B : x bf16 row-major
    uint4* xbT  = (uint4*)(ws + 67764224);     // 67,108,864 B : x bf16 j-contiguous frag order

    hipMemsetAsync(s, 0, 131072, stream);
    k_pre<<<dim3(32, BATCH), 256, 0, stream>>>(x, W, xbT, xb, s, (uint2*)Wb, (uint2*)WT);
    k_fused<<<BATCH, 1024, 0, stream>>>(xb, xbT, s, Wb, WT, out);
}

// Round 4
// 341.727 us; speedup vs baseline: 1.5944x; 1.5944x over previous
//
#include <hip/hip_runtime.h>

typedef unsigned int u32;
typedef unsigned short u16;
typedef float f32x4 __attribute__((ext_vector_type(4)));
typedef __bf16 bf16x8 __attribute__((ext_vector_type(8)));

#define BATCH 128
#define NIN   1024
#define DIN   256
#define NC    16
#define DC    32
#define NCOL  512

__device__ __forceinline__ float bflo(u32 v){ return __uint_as_float(v << 16); }
__device__ __forceinline__ float bfhi(u32 v){ return __uint_as_float(v & 0xffff0000u); }
__device__ __forceinline__ u32 bfround(u32 ua){ return (ua + 0x7fffu + ((ua >> 16) & 1u)) >> 16; }
__device__ __forceinline__ u32 pack2(float a, float b){
    return (bfround(__float_as_uint(a)) & 0xffffu) | (bfround(__float_as_uint(b)) << 16);
}
__device__ __forceinline__ bf16x8 ldfrag(const u16* p){
    return __builtin_bit_cast(bf16x8, *(const uint4*)p);
}

// Swizzled address (bf16 units) for a [R][256] bf16 LDS tile (R<=128).
// Round-3-verified for: 16B row-chunk writes/reads (d%8==0), column u16 gathers.
__device__ __forceinline__ int lds_x(int r, int d){
    int sw = (d >> 2) ^ ((r & 7) << 1) ^ (((r >> 3) & 3) << 2);
    return r * 256 + (sw << 2) + (d & 3);
}

// K0: pure streaming — x fp32 -> xb bf16 row-major, col-sums -> s, W -> Wb/WT.
__global__ __launch_bounds__(256) void k_pre(const float* __restrict__ x, const float* __restrict__ W,
                                             u16* __restrict__ xb, float* __restrict__ s,
                                             uint2* __restrict__ Wb, uint2* __restrict__ WT){
    const int t = threadIdx.x, seg = blockIdx.x, b = blockIdx.y;

    if (seg == 0){   // W conversions: 128 (b) blocks cover all 32768 float4s of W
        int id = b * 256 + t;
        float4 w4 = ((const float4*)W)[id];
        Wb[id] = make_uint2(pack2(w4.x, w4.y), pack2(w4.z, w4.w));
        int c = id >> 6, d4 = id & 63;           // WT[c][4*d4 .. +3]
        float e0 = W[(size_t)(d4 * 4 + 0) * NCOL + c];
        float e1 = W[(size_t)(d4 * 4 + 1) * NCOL + c];
        float e2 = W[(size_t)(d4 * 4 + 2) * NCOL + c];
        float e3 = W[(size_t)(d4 * 4 + 3) * NCOL + c];
        WT[c * 64 + d4] = make_uint2(pack2(e0, e1), pack2(e2, e3));
    }
    const float4* xg = (const float4*)(x + ((size_t)b * NIN + seg * 64) * DIN);
    uint2* xbw = (uint2*)xb + ((size_t)(b * NIN + seg * 64)) * 64;
    int d4 = t & 63, r0 = t >> 6;
    float cs0 = 0.f, cs1 = 0.f, cs2 = 0.f, cs3 = 0.f;
    #pragma unroll
    for (int m = 0; m < 16; m++){
        int r = r0 + 4 * m;
        float4 v = xg[r * 64 + d4];
        uint2 p = make_uint2(pack2(v.x, v.y), pack2(v.z, v.w));
        xbw[r * 64 + d4] = p;
        cs0 += bflo(p.x); cs1 += bfhi(p.x);
        cs2 += bflo(p.y); cs3 += bfhi(p.y);
    }
    atomicAdd(&s[b * DIN + d4 * 4 + 0], cs0);
    atomicAdd(&s[b * DIN + d4 * 4 + 1], cs1);
    atomicAdd(&s[b * DIN + d4 * 4 + 2], cs2);
    atomicAdd(&s[b * DIN + d4 * 4 + 3], cs3);
}

// K1: per (b, 128-row j-chunk): stage x tile in LDS once; bb = v.x^T (MFMA,
//     row-major frags); softmax over i; z partial = c.x (MFMA, B-frag via
//     column u16 gather from the SAME LDS tile); atomicAdd into zg.
__global__ __launch_bounds__(256) void k_main(const u16* __restrict__ xb, const u16* __restrict__ vb,
                                              float* __restrict__ zg){
    __shared__ __align__(16) u16 xt[128 * 256];   // 64 KB
    __shared__ float bbl[16][132];                //  8.25 KB
    __shared__ __align__(16) u16 cl[16][136];     //  4.25 KB (272B pitch, 16B-aligned)
    const int t = threadIdx.x, jh = blockIdx.x, b = blockIdx.y;
    const int lane = t & 63, wv = t >> 6;
    const int l15 = lane & 15, q = lane >> 4;

    // v A-fragments from global (independent of LDS; issued before staging completes)
    uint4 vf[8];
    #pragma unroll
    for (int ks = 0; ks < 8; ks++)
        vf[ks] = *(const uint4*)&vb[((size_t)b * 16 + l15) * 256 + ks * 32 + q * 8];

    // stage 128x256 bf16 tile (coalesced uint4 loads, swizzled 16B LDS writes)
    {
        const uint4* xg = (const uint4*)(xb + ((size_t)(b * NIN + jh * 128)) * 256);
        #pragma unroll
        for (int m = 0; m < 16; m++){
            int id = t + 256 * m;                 // 0..4095
            int row = id >> 5, c8 = id & 31;
            uint4 v = xg[id];
            *(uint4*)&xt[lds_x(row, c8 * 8)] = v;
        }
    }
    __syncthreads();

    // phase A: bb[i,j] — A = v frags, B = x row-major frags from LDS
    #pragma unroll
    for (int u = 0; u < 2; u++){
        int jt = wv * 2 + u;                      // 8 j-tiles / 4 waves
        f32x4 acc = {0.f, 0.f, 0.f, 0.f};
        #pragma unroll
        for (int ks = 0; ks < 8; ks++)
            acc = __builtin_amdgcn_mfma_f32_16x16x32_bf16(
                __builtin_bit_cast(bf16x8, vf[ks]),
                ldfrag(&xt[lds_x(jt * 16 + l15, ks * 32 + q * 8)]), acc, 0, 0, 0);
        #pragma unroll
        for (int r = 0; r < 4; r++) bbl[q * 4 + r][jt * 16 + l15] = acc[r];   // row=i, col=j
    }
    __syncthreads();

    // phase B: softmax over i per column j
    if (t < 128){
        float mx = -1e30f, e[16], sum = 0.f;
        #pragma unroll
        for (int i = 0; i < 16; i++) mx = fmaxf(mx, bbl[i][t]);
        #pragma unroll
        for (int i = 0; i < 16; i++){ e[i] = __expf(bbl[i][t] - mx); sum += e[i]; }
        float inv = 1.f / sum;
        #pragma unroll
        for (int i = 0; i < 16; i++) cl[i][t] = (u16)bfround(__float_as_uint(e[i] * inv));
    }
    __syncthreads();

    // phase C: z[i,d] partial — A = c frags, B = x^T frags gathered from LDS
    #pragma unroll
    for (int u = 0; u < 4; u++){
        int dt = wv * 4 + u;                      // 16 d-tiles / 4 waves
        f32x4 acc = {0.f, 0.f, 0.f, 0.f};
        #pragma unroll
        for (int js = 0; js < 4; js++){
            u32 w[4];
            #pragma unroll
            for (int e2 = 0; e2 < 4; e2++){
                u32 lo = xt[lds_x(js * 32 + q * 8 + 2 * e2,     dt * 16 + l15)];
                u32 hi = xt[lds_x(js * 32 + q * 8 + 2 * e2 + 1, dt * 16 + l15)];
                w[e2] = lo | (hi << 16);
            }
            bf16x8 cf = ldfrag(&cl[l15][js * 32 + q * 8]);
            acc = __builtin_amdgcn_mfma_f32_16x16x32_bf16(
                cf, __builtin_bit_cast(bf16x8, make_uint4(w[0], w[1], w[2], w[3])), acc, 0, 0, 0);
        }
        #pragma unroll
        for (int r = 0; r < 4; r++)
            atomicAdd(&zg[((size_t)b * 16 + q * 4 + r) * 256 + dt * 16 + l15], acc[r]);
    }
}

// K2: per (b, half): 8 capsules. y = z.W (zg read+zero), squash, v = o.W via WT.
__global__ __launch_bounds__(256) void k_tail(const float* __restrict__ s, float* __restrict__ zg,
                                              const u16* __restrict__ Wb, const u32* __restrict__ WT32,
                                              u16* __restrict__ vb, float* __restrict__ out, int mode){
    __shared__ float zl[8][260];
    __shared__ __align__(16) float ol[256];
    const int ih2 = blockIdx.x, b = blockIdx.y, t = threadIdx.x;
    const int i_loc = t >> 5;                     // 0..7
    const int o_idx = ih2 * 256 + t;              // global (i,k) flat index
    float y = 0.f;
    if (mode == 0){
        zl[0][t] = s[b * 256 + t] * (1.f / 16.f);
        __syncthreads();
        #pragma unroll 8
        for (int d = 0; d < 256; d++) y += zl[0][d] * bflo((u32)Wb[d * 512 + o_idx]);
    } else {
        #pragma unroll
        for (int u0 = 0; u0 < 8; u0++){
            int idx = t + 256 * u0;               // (ii, dd) over 8x256
            int ii = idx >> 8, dd = idx & 255;
            size_t a = ((size_t)b * 16 + ih2 * 8 + ii) * 256 + dd;
            float acc = zg[a];
            if (mode == 1) zg[a] = 0.f;           // ready for next iteration's atomics
            zl[ii][dd] = acc;
        }
        __syncthreads();
        #pragma unroll 8
        for (int d = 0; d < 256; d++) y += zl[i_loc][d] * bflo((u32)Wb[d * 512 + o_idx]);
    }
    // squash (unit-norm over the 32 k-lanes of each capsule)
    float s2 = y * y;
    s2 += __shfl_xor(s2, 1); s2 += __shfl_xor(s2, 2); s2 += __shfl_xor(s2, 4);
    s2 += __shfl_xor(s2, 8); s2 += __shfl_xor(s2, 16);
    float r = y / sqrtf(s2 + 1e-7f);
    if (mode == 2){ out[b * 512 + o_idx] = r; return; }
    ol[t] = r;
    __syncthreads();
    // v-pass: thread owns d-pair dh; 4 capsules of this half (coalesced WT reads)
    {
        int dh = t & 127, ihalf = t >> 7;
        #pragma unroll
        for (int e = 0; e < 4; e++){
            int ii = ihalf * 4 + e;
            int i2 = ih2 * 8 + ii;
            float a0 = 0.f, a1 = 0.f;
            #pragma unroll
            for (int k = 0; k < 32; k++){
                u32 wv2 = WT32[(size_t)(i2 * 32 + k) * 128 + dh];
                float ok = ol[ii * 32 + k];
                a0 += ok * bflo(wv2); a1 += ok * bfhi(wv2);
            }
            ((u32*)vb)[(size_t)(b * 16 + i2) * 128 + dh] = pack2(a0, a1);
        }
    }
}

extern "C" void kernel_launch(void* const* d_in, const int* in_sizes, int n_in,
                              void* d_out, int out_size, void* d_ws, size_t ws_size,
                              hipStream_t stream){
    const float* x = (const float*)d_in[0];    // fp32 [128][1024][256]
    const float* W = (const float*)d_in[1];    // fp32 [256][512]
    float* out = (float*)d_out;                // fp32 [128][16][32]
    char* ws = (char*)d_ws;                    // ~71 MB used
    float* s    = (float*)(ws);                //   131,072 B : column sums
    float* zg   = (float*)(ws + 131072);       // 2,097,152 B : z accumulator [128][16][256]
    u16*   Wb   = (u16*)  (ws + 2228224);      //   262,144 B : W bf16 [d][c]
    u32*   WT   = (u32*)  (ws + 2490368);      //   262,144 B : W^T bf16 [c][d]
    u16*   vb   = (u16*)  (ws + 2752512);      // 1,048,576 B : v = o.W-slices, bf16
    u16*   xb   = (u16*)  (ws + 3801088);      // 67,108,864 B : x bf16 row-major

    hipMemsetAsync(ws, 0, 2228224, stream);    // s + zg in one shot
    k_pre<<<dim3(16, BATCH), 256, 0, stream>>>(x, W, xb, s, (uint2*)Wb, (uint2*)WT);
    k_tail<<<dim3(2, BATCH), 256, 0, stream>>>(s, zg, Wb, WT, vb, out, 0);
    for (int it = 1; it < 4; it++){
        k_main<<<dim3(8, BATCH), 256, 0, stream>>>(xb, vb, zg);
        k_tail<<<dim3(2, BATCH), 256, 0, stream>>>(s, zg, Wb, WT, vb, out, it == 3 ? 2 : 1);
    }
}